// Round 21
// baseline (1214.300 us; speedup 1.0000x reference)
//
#include <hip/hip_runtime.h>

typedef __attribute__((ext_vector_type(8))) _Float16 half8;
typedef __attribute__((ext_vector_type(4))) _Float16 half4;
typedef __attribute__((ext_vector_type(4))) float f32x4;

#define HDIM 768
#define LNEPS 1e-5f

// fused_kernel LDS map (bytes)
#define L_AS   0        // 2 x 12288  (A staging: 192x32 fp16 per buf)
#define L_BS   24576    // 2 x 16384  (B staging: 256x32 fp16 per buf)
#define L_STQ  57344    // 192 x 264  (stash half 0: cols 0..127 of n-tile)
#define L_STK  108032   // 192 x 264  (stash half 1: cols 128..255)
#define L_SP   158720   // 576 f32 (scores pos; coef overwrites after n=5)
#define L_SN   161024   // 576 f32 (scores neg)
#define L_TOT  163328
#define SSTR   264      // stash row stride bytes (8B-aligned, bank-spread)

__device__ __forceinline__ void gload_lds16(const void* g, void* l) {
  __builtin_amdgcn_global_load_lds(
      (const __attribute__((address_space(1))) void*)g,
      (__attribute__((address_space(3))) void*)l, 16, 0, 0);
}

// ---------------- Wvo = Wo @ Wv -> fp16 fused rows 1536..2303; bvo = Wo@bv ---
__global__ __launch_bounds__(256) void wvo_kernel(
    const float* __restrict__ Wo, const float* __restrict__ Wv,
    const float* __restrict__ bv,
    _Float16* __restrict__ Wvo, float* __restrict__ bvo)
{
  if (blockIdx.x == 144) {
    for (int o = threadIdx.x; o < 768; o += 256) {
      float s = 0.f;
      for (int h = 0; h < 768; ++h) s += Wo[o * 768 + h] * bv[h];
      bvo[o] = s;
    }
    return;
  }
  __shared__ float As[64][65];
  __shared__ float Bs[64][65];
  const int bm = blockIdx.x / 12, bn = blockIdx.x % 12;
  const int tid = threadIdx.x;
  const int tr = tid >> 4, tc = tid & 15;
  float acc[4][4] = {};
  for (int k0 = 0; k0 < 768; k0 += 64) {
    __syncthreads();
#pragma unroll
    for (int i = 0; i < 16; ++i) {
      const int e = i * 256 + tid, r = e >> 6, c = e & 63;
      As[r][c] = Wo[(bm * 64 + r) * 768 + (k0 + c)];
      Bs[r][c] = Wv[(k0 + r) * 768 + (bn * 64 + c)];
    }
    __syncthreads();
#pragma unroll 8
    for (int k = 0; k < 64; ++k) {
      float a[4], b[4];
#pragma unroll
      for (int i = 0; i < 4; ++i) a[i] = As[tr * 4 + i][k];
#pragma unroll
      for (int j = 0; j < 4; ++j) b[j] = Bs[k][tc * 4 + j];
#pragma unroll
      for (int i = 0; i < 4; ++i)
#pragma unroll
        for (int j = 0; j < 4; ++j) acc[i][j] += a[i] * b[j];
    }
  }
#pragma unroll
  for (int i = 0; i < 4; ++i)
#pragma unroll
    for (int j = 0; j < 4; ++j)
      Wvo[(bm * 64 + tr * 4 + i) * 768 + bn * 64 + tc * 4 + j] = (_Float16)acc[i][j];
}

// ---------------- prep: LayerNorm (blocks 0..49151) + weight convert ---------
// Blocks >= 49152 build interleaved fused weight rows 0..1535 + biases
// (fused row orow = 256n + c: c<128 -> Wq[128n+c], else Wk[128n+c-128]);
// merged into the LN grid to remove one serialized dispatch (R20).
__global__ __launch_bounds__(256) void prep_kernel(
    const float* __restrict__ feat, const float* __restrict__ gamma,
    const float* __restrict__ beta, _Float16* __restrict__ xout,
    const float* __restrict__ Wq, const float* __restrict__ Wk,
    const float* __restrict__ bq, const float* __restrict__ bk,
    _Float16* __restrict__ Wf, float* __restrict__ biasf)
{
  if (blockIdx.x >= 49152) {
    // ---- convert part (verbatim body, re-based block index) ----
    const long NW = 1536L * 768;
    long i = (long)(blockIdx.x - 49152) * 256 + threadIdx.x;
    if (i < NW) {
      const int orow = (int)(i / 768);
      const int k = (int)(i - (long)orow * 768);
      const int n = orow >> 8, c = orow & 255;
      const int src = n * 128 + (c & 127);
      Wf[i] = (_Float16)((c < 128) ? Wq[(long)src * 768 + k]
                                   : Wk[(long)src * 768 + k]);
    } else if (i < NW + 1536) {
      const int j = (int)(i - NW);
      const int n = j >> 8, c = j & 255;
      const int src = n * 128 + (c & 127);
      biasf[j] = (c < 128) ? bq[src] : bk[src];
    }
    return;
  }
  // ---- LayerNorm part: one wave per row of 768, fp16 out ----
  const int w = threadIdx.x >> 6, lane = threadIdx.x & 63;
  const long row = (long)blockIdx.x * 4 + w;
  const float* fr = feat + row * HDIM;
  float4 v[3];
  float s = 0.f, ss = 0.f;
#pragma unroll
  for (int i = 0; i < 3; ++i) {
    v[i] = *(const float4*)&fr[(i * 64 + lane) * 4];
    s  += v[i].x + v[i].y + v[i].z + v[i].w;
    ss += v[i].x * v[i].x + v[i].y * v[i].y + v[i].z * v[i].z + v[i].w * v[i].w;
  }
#pragma unroll
  for (int off = 32; off; off >>= 1) {
    s  += __shfl_xor(s, off);
    ss += __shfl_xor(ss, off);
  }
  const float mu = s * (1.f / 768.f);
  const float var = ss * (1.f / 768.f) - mu * mu;
  const float rs = rsqrtf(var + LNEPS);
#pragma unroll
  for (int i = 0; i < 3; ++i) {
    const int idx = (i * 64 + lane) * 4;
    float4 g4 = *(const float4*)&gamma[idx];
    float4 b4 = *(const float4*)&beta[idx];
    half4 o;
    o[0] = (_Float16)((v[i].x - mu) * rs * g4.x + b4.x);
    o[1] = (_Float16)((v[i].y - mu) * rs * g4.y + b4.y);
    o[2] = (_Float16)((v[i].z - mu) * rs * g4.z + b4.z);
    o[3] = (_Float16)((v[i].w - mu) * rs * g4.w + b4.w);
    *(half4*)&xout[row * HDIM + idx] = o;
  }
}

// ---------------- fused panel GEMM + attention + output ----------------
// Block = 192 rows (64 batches) x 2304 fused cols in 9 n-tiles of 256.
// 512 threads / 8 waves (2M x 4N, wave tile 96x64), depth-2 prefetch with
// per-group counted vmcnt(3)/vmcnt(4), raw barriers, zero-conflict XOR layout.
// R16 (final): K-loop unrolled x2 with STATIC buffer indices (all LDS offsets
// fold to immediates); verified best configuration (1193.6 us total w/ R20).
__global__ __launch_bounds__(512, 1) void fused_kernel(
    const _Float16* __restrict__ xh,
    const _Float16* __restrict__ Wf,
    const float* __restrict__ bias,
    const float* __restrict__ bo,
    float* __restrict__ out)
{
  __shared__ __align__(16) char lds[L_TOT];
  const int tid = threadIdx.x;
  const int lane = tid & 63;
  const int quad = lane >> 4, l16 = lane & 15;
  const int w = tid >> 6;
  const int wm = w >> 2, wn = w & 3;

  const int nwg = gridDim.x;
  const int orig = blockIdx.x;
  const int bid = (orig & 7) * (nwg >> 3) + (orig >> 3);
  const long m0 = (long)bid * 192;

  // zero score accumulators (sp+sn contiguous: 1152 floats)
  {
    float* sc = (float*)(lds + L_SP);
#pragma unroll
    for (int i = 0; i < 3; ++i) {
      const int idx = i * 512 + tid;
      if (idx < 1152) sc[idx] = 0.f;
    }
  }

  // staging maps. A: 768 16B-chunks (192 rows x 4), waves 0-3, 3 issues.
  //               B: 1024 chunks (256 rows x 4), waves 4-7, 4 issues.
  // physical slot p of row r holds logical chunk cc = p ^ ((r>>1)&3).
  const int wg = w & 3;
  long aOff[3]; int aLds[3];
#pragma unroll
  for (int i = 0; i < 3; ++i) {
    const int c = i * 256 + wg * 64 + lane, r = c >> 2, p = c & 3;
    const int cc = p ^ ((r >> 1) & 3);
    aOff[i] = (m0 + r) * HDIM + cc * 8;
    aLds[i] = c * 16;
  }
  long bOff[4]; int bLds[4];
#pragma unroll
  for (int i = 0; i < 4; ++i) {
    const int c = i * 256 + wg * 64 + lane, r = c >> 2, p = c & 3;
    const int cc = p ^ ((r >> 1) & 3);
    bOff[i] = (long)r * HDIM + cc * 8;
    bLds[i] = c * 16;
  }

  long stg_k = 0, stg_nb = 0;
#define STAGE(BUF_)                                                           \
  do {                                                                        \
    if (w < 4) {                                                              \
      _Pragma("unroll")                                                       \
      for (int i_ = 0; i_ < 3; ++i_)                                          \
        gload_lds16(xh + aOff[i_] + stg_k, lds + L_AS + (BUF_) * 12288 + aLds[i_]); \
    } else {                                                                  \
      _Pragma("unroll")                                                       \
      for (int i_ = 0; i_ < 4; ++i_)                                          \
        gload_lds16(Wf + stg_nb + bOff[i_] + stg_k, lds + L_BS + (BUF_) * 16384 + bLds[i_]); \
    }                                                                         \
    stg_k += 32;                                                              \
    if (stg_k == HDIM) { stg_k = 0; stg_nb += 256L * HDIM; }                  \
  } while (0)
#define VMW()                                                                 \
  do { if (w < 4) { asm volatile("s_waitcnt vmcnt(3)" ::: "memory"); }        \
       else       { asm volatile("s_waitcnt vmcnt(4)" ::: "memory"); } } while (0)
#define SB0() __builtin_amdgcn_sched_barrier(0)

  f32x4 acc[6][4];
#pragma unroll
  for (int mi = 0; mi < 6; ++mi)
#pragma unroll
    for (int ni = 0; ni < 4; ++ni)
#pragma unroll
      for (int j = 0; j < 4; ++j) acc[mi][ni][j] = 0.f;

// One K-step with STATIC buffer index BUF_ (runtime step id s_ only gates
// the staging/wait tail). Stage(s+2) targets buf[(s+2)&1] == BUF_.
#define STEPK(BUF_, s_)                                                       \
  do {                                                                        \
    const char* as_ = lds + L_AS + (BUF_) * 12288;                            \
    const char* bs_ = lds + L_BS + (BUF_) * 16384;                            \
    half8 af[6], bf[4];                                                       \
    _Pragma("unroll")                                                         \
    for (int mi_ = 0; mi_ < 6; ++mi_) {                                       \
      const int r_ = wm * 96 + mi_ * 16 + l16;                                \
      af[mi_] = *(const half8*)(as_ + r_ * 64 + ((quad ^ ((r_ >> 1) & 3)) * 16)); \
    }                                                                         \
    _Pragma("unroll")                                                         \
    for (int ni_ = 0; ni_ < 4; ++ni_) {                                       \
      const int r_ = wn * 64 + ni_ * 16 + l16;                                \
      bf[ni_] = *(const half8*)(bs_ + r_ * 64 + ((quad ^ ((r_ >> 1) & 3)) * 16)); \
    }                                                                         \
    __builtin_amdgcn_s_setprio(1);                                            \
    _Pragma("unroll")                                                         \
    for (int mi_ = 0; mi_ < 6; ++mi_)                                         \
      _Pragma("unroll")                                                       \
      for (int ni_ = 0; ni_ < 4; ++ni_)                                       \
        acc[mi_][ni_] = __builtin_amdgcn_mfma_f32_16x16x32_f16(               \
            af[mi_], bf[ni_], acc[mi_][ni_], 0, 0, 0);                        \
    __builtin_amdgcn_s_setprio(0);                                            \
    SB0();                                                                    \
    __builtin_amdgcn_s_barrier();          /* all waves done reading buf */   \
    SB0();                                                                    \
    if ((s_) + 2 < 216) STAGE(BUF_);       /* overwrite just-consumed buf */  \
    if ((s_) < 214) {                                                         \
      VMW();                               /* step s+1 landed */              \
      __builtin_amdgcn_s_barrier();                                           \
      SB0();                                                                  \
    } else if ((s_) == 214) {                                                 \
      asm volatile("s_waitcnt vmcnt(0)" ::: "memory");  /* tail */            \
      __builtin_amdgcn_s_barrier();                                           \
      SB0();                                                                  \
    }                                                                         \
  } while (0)

  STAGE(0); STAGE(1);
  VMW();                                   // K-step 0 landed (own loads)
  __builtin_amdgcn_s_barrier();
  SB0();

  for (int n = 0; n < 9; ++n) {
    for (int ks2 = 0; ks2 < 12; ++ks2) {
      const int sbase = n * 24 + ks2 * 2;
      STEPK(0, sbase);
      STEPK(1, sbase + 1);
    }

    // ---- phase end for n-tile n: bias + stash write (fp16), zero acc ----
    {
      float bv[4];
#pragma unroll
      for (int ni = 0; ni < 4; ++ni)
        bv[ni] = bias[n * 256 + wn * 64 + ni * 16 + l16];
      char* st = lds + ((wn >> 1) ? L_STK : L_STQ);
      const int cb = (wn & 1) * 64;
#pragma unroll
      for (int mi = 0; mi < 6; ++mi)
#pragma unroll
        for (int ni = 0; ni < 4; ++ni)
#pragma unroll
          for (int j = 0; j < 4; ++j) {
            const int row = wm * 96 + mi * 16 + quad * 4 + j;
            *(_Float16*)(st + row * SSTR + (cb + ni * 16 + l16) * 2) =
                (_Float16)(acc[mi][ni][j] + bv[ni]);
          }
#pragma unroll
      for (int mi = 0; mi < 6; ++mi)
#pragma unroll
        for (int ni = 0; ni < 4; ++ni)
#pragma unroll
          for (int j = 0; j < 4; ++j) acc[mi][ni][j] = 0.f;
    }
    __builtin_amdgcn_s_barrier();

    if (n < 6) {
      // score accumulation: 8 threads per batch, each a 16-elem h-segment
      const int b = tid >> 3, sub = tid & 7;
      half4 qv[3][4], kv[3][4];
#pragma unroll
      for (int t = 0; t < 3; ++t) {
        const char* rq = lds + L_STQ + (3 * b + t) * SSTR + sub * 32;
        const char* rk = lds + L_STK + (3 * b + t) * SSTR + sub * 32;
#pragma unroll
        for (int u = 0; u < 4; ++u) {
          qv[t][u] = *(const half4*)(rq + u * 8);
          kv[t][u] = *(const half4*)(rk + u * 8);
        }
      }
#pragma unroll
      for (int qi = 0; qi < 3; ++qi)
#pragma unroll
        for (int ki = 0; ki < 3; ++ki) {
          float p = 0.f, nn = 0.f;
#pragma unroll
          for (int u = 0; u < 4; ++u)
#pragma unroll
            for (int e = 0; e < 4; ++e) {
              const float qq = (float)qv[qi][u][e];
              const float kk = (float)kv[ki][u][e];
              p  += fmaxf(qq, 0.f) * fmaxf(kk, 0.f);
              nn += fminf(qq, 0.f) * fminf(kk, 0.f);
            }
          p  += __shfl_xor(p, 1);  p  += __shfl_xor(p, 2);  p  += __shfl_xor(p, 4);
          nn += __shfl_xor(nn, 1); nn += __shfl_xor(nn, 2); nn += __shfl_xor(nn, 4);
          if (sub == 0) {
            ((float*)(lds + L_SP))[b * 9 + qi * 3 + ki] += p;
            ((float*)(lds + L_SN))[b * 9 + qi * 3 + ki] += nn;
          }
        }
      __builtin_amdgcn_s_barrier();
      if (n == 5) {
        if (tid < 64) {   // softmax coefs; coef overwrites sp in place
          float* sp = (float*)(lds + L_SP) + tid * 9;
          float* sn = (float*)(lds + L_SN) + tid * 9;
          const float scale = 0.03608439182435161f;  // 768^-0.5
#pragma unroll
          for (int qi = 0; qi < 3; ++qi) {
            const float p0 = sp[qi*3+0]*scale, p1 = sp[qi*3+1]*scale, p2 = sp[qi*3+2]*scale;
            const float n0 = sn[qi*3+0]*scale, n1 = sn[qi*3+1]*scale, n2 = sn[qi*3+2]*scale;
            const float mp = fmaxf(p0, fmaxf(p1, p2));
            const float mn = fmaxf(n0, fmaxf(n1, n2));
            const float ep0 = __expf(p0-mp), ep1 = __expf(p1-mp), ep2 = __expf(p2-mp);
            const float en0 = __expf(n0-mn), en1 = __expf(n1-mn), en2 = __expf(n2-mn);
            const float rp = 1.f / (ep0+ep1+ep2), rn = 1.f / (en0+en1+en2);
            sp[qi*3+0] = ep0*rp - en0*rn;
            sp[qi*3+1] = ep1*rp - en1*rn;
            sp[qi*3+2] = ep2*rp - en2*rn;
          }
        }
        __builtin_amdgcn_s_barrier();
      }
    } else {
      // VO epilogue: out[row] = xh + bo + sum_ki coef[t][ki] * VO[3b+ki]
      const int cg = tid & 63, rg = tid >> 6;     // 64 col-groups x 8 row-groups
      const int c = cg * 4;
      const char* vb = lds + ((c >> 7) ? L_STK : L_STQ) + (c & 127) * 2;
      const long gc = 256L * (n - 6) + c;
      const f32x4 bov = *(const f32x4*)&bo[gc];
      const float* cf0 = (const float*)(lds + L_SP);
#pragma unroll 4
      for (int rr = 0; rr < 24; ++rr) {
        const int row = rr * 8 + rg;
        const int b = (int)((unsigned)row / 3u);
        const int t = row - 3 * b;
        const float* cf = cf0 + b * 9 + t * 3;
        const half4 v0 = *(const half4*)(vb + (3 * b + 0) * SSTR);
        const half4 v1 = *(const half4*)(vb + (3 * b + 1) * SSTR);
        const half4 v2 = *(const half4*)(vb + (3 * b + 2) * SSTR);
        const half4 hx = *(const half4*)&xh[(m0 + row) * HDIM + gc];
        const float c0 = cf[0], c1 = cf[1], c2 = cf[2];
        f32x4 o;
#pragma unroll
        for (int j = 0; j < 4; ++j)
          o[j] = (float)hx[j] + bov[j] + c0 * (float)v0[j]
               + c1 * (float)v1[j] + c2 * (float)v2[j];
        *(f32x4*)&out[(m0 + row) * HDIM + gc] = o;
      }
      __builtin_amdgcn_s_barrier();
    }
  }
#undef STAGE
#undef VMW
#undef SB0
#undef STEPK
}

extern "C" void kernel_launch(void* const* d_in, const int* in_sizes, int n_in,
                              void* d_out, int out_size, void* d_ws, size_t ws_size,
                              hipStream_t stream) {
  (void)in_sizes; (void)n_in; (void)out_size; (void)ws_size;
  const float* feat = (const float*)d_in[0];
  const float* Wq   = (const float*)d_in[1];
  const float* bq   = (const float*)d_in[2];
  const float* Wk   = (const float*)d_in[3];
  const float* bk   = (const float*)d_in[4];
  const float* Wv   = (const float*)d_in[5];
  const float* bv   = (const float*)d_in[6];
  const float* Wo   = (const float*)d_in[7];
  const float* bo   = (const float*)d_in[8];
  const float* ln_g = (const float*)d_in[9];
  const float* ln_b = (const float*)d_in[10];

  char* ws = (char*)d_ws;
  // layout: xh [196608*768] fp16 @ 0            (301,989,888)
  //         Wf [2304*768]  fp16 @ 301,989,888   (3,538,944)
  //         biasf [2304]   fp32 @ 305,528,832   (9,216)
  _Float16* xh    = (_Float16*)(ws);
  _Float16* Wf    = (_Float16*)(ws + 301989888L);
  float*    biasf = (float*)   (ws + 305528832L);

  wvo_kernel<<<145, 256, 0, stream>>>(Wo, Wv, bv, Wf + 1536L * 768, biasf + 1536);
  // prep: LN (49152 blocks) + QK weight convert (4614 blocks) in one dispatch
  prep_kernel<<<53766, 256, 0, stream>>>(feat, ln_g, ln_b, xh,
                                         Wq, Wk, bq, bk, Wf, biasf);
  fused_kernel<<<1024, 512, 0, stream>>>(xh, Wf, biasf, bo, (float*)d_out);
}

// Round 22
// 1191.164 us; speedup vs baseline: 1.0194x; 1.0194x over previous
//
#include <hip/hip_runtime.h>

typedef __attribute__((ext_vector_type(8))) _Float16 half8;
typedef __attribute__((ext_vector_type(4))) _Float16 half4;
typedef __attribute__((ext_vector_type(4))) float f32x4;

#define HDIM 768
#define LNEPS 1e-5f

// fused_kernel LDS map (bytes)
#define L_AS   0        // 2 x 12288  (A staging: 192x32 fp16 per buf)
#define L_BS   24576    // 2 x 16384  (B staging: 256x32 fp16 per buf)
#define L_STQ  57344    // 192 x 264  (stash half 0: cols 0..127 of n-tile)
#define L_STK  108032   // 192 x 264  (stash half 1: cols 128..255)
#define L_SP   158720   // 576 f32 (scores pos; coef overwrites after n=5)
#define L_SN   161024   // 576 f32 (scores neg)
#define L_TOT  163328
#define SSTR   264      // stash row stride bytes (8B-aligned, bank-spread)

__device__ __forceinline__ void gload_lds16(const void* g, void* l) {
  __builtin_amdgcn_global_load_lds(
      (const __attribute__((address_space(1))) void*)g,
      (__attribute__((address_space(3))) void*)l, 16, 0, 0);
}

// ---------------- Wvo = Wo @ Wv -> fp16 fused rows 1536..2303; bvo = Wo@bv ---
__global__ __launch_bounds__(256) void wvo_kernel(
    const float* __restrict__ Wo, const float* __restrict__ Wv,
    const float* __restrict__ bv,
    _Float16* __restrict__ Wvo, float* __restrict__ bvo)
{
  if (blockIdx.x == 144) {
    for (int o = threadIdx.x; o < 768; o += 256) {
      float s = 0.f;
      for (int h = 0; h < 768; ++h) s += Wo[o * 768 + h] * bv[h];
      bvo[o] = s;
    }
    return;
  }
  __shared__ float As[64][65];
  __shared__ float Bs[64][65];
  const int bm = blockIdx.x / 12, bn = blockIdx.x % 12;
  const int tid = threadIdx.x;
  const int tr = tid >> 4, tc = tid & 15;
  float acc[4][4] = {};
  for (int k0 = 0; k0 < 768; k0 += 64) {
    __syncthreads();
#pragma unroll
    for (int i = 0; i < 16; ++i) {
      const int e = i * 256 + tid, r = e >> 6, c = e & 63;
      As[r][c] = Wo[(bm * 64 + r) * 768 + (k0 + c)];
      Bs[r][c] = Wv[(k0 + r) * 768 + (bn * 64 + c)];
    }
    __syncthreads();
#pragma unroll 8
    for (int k = 0; k < 64; ++k) {
      float a[4], b[4];
#pragma unroll
      for (int i = 0; i < 4; ++i) a[i] = As[tr * 4 + i][k];
#pragma unroll
      for (int j = 0; j < 4; ++j) b[j] = Bs[k][tc * 4 + j];
#pragma unroll
      for (int i = 0; i < 4; ++i)
#pragma unroll
        for (int j = 0; j < 4; ++j) acc[i][j] += a[i] * b[j];
    }
  }
#pragma unroll
  for (int i = 0; i < 4; ++i)
#pragma unroll
    for (int j = 0; j < 4; ++j)
      Wvo[(bm * 64 + tr * 4 + i) * 768 + bn * 64 + tc * 4 + j] = (_Float16)acc[i][j];
}

// ---------------- prep: LayerNorm (blocks 0..49151) + weight convert ---------
// Blocks >= 49152 build interleaved fused weight rows 0..1535 + biases
// (fused row orow = 256n + c: c<128 -> Wq[128n+c], else Wk[128n+c-128]);
// merged into the LN grid to remove one serialized dispatch (R20).
__global__ __launch_bounds__(256) void prep_kernel(
    const float* __restrict__ feat, const float* __restrict__ gamma,
    const float* __restrict__ beta, _Float16* __restrict__ xout,
    const float* __restrict__ Wq, const float* __restrict__ Wk,
    const float* __restrict__ bq, const float* __restrict__ bk,
    _Float16* __restrict__ Wf, float* __restrict__ biasf)
{
  if (blockIdx.x >= 49152) {
    // ---- convert part (verbatim body, re-based block index) ----
    const long NW = 1536L * 768;
    long i = (long)(blockIdx.x - 49152) * 256 + threadIdx.x;
    if (i < NW) {
      const int orow = (int)(i / 768);
      const int k = (int)(i - (long)orow * 768);
      const int n = orow >> 8, c = orow & 255;
      const int src = n * 128 + (c & 127);
      Wf[i] = (_Float16)((c < 128) ? Wq[(long)src * 768 + k]
                                   : Wk[(long)src * 768 + k]);
    } else if (i < NW + 1536) {
      const int j = (int)(i - NW);
      const int n = j >> 8, c = j & 255;
      const int src = n * 128 + (c & 127);
      biasf[j] = (c < 128) ? bq[src] : bk[src];
    }
    return;
  }
  // ---- LayerNorm part: one wave per row of 768, fp16 out ----
  const int w = threadIdx.x >> 6, lane = threadIdx.x & 63;
  const long row = (long)blockIdx.x * 4 + w;
  const float* fr = feat + row * HDIM;
  float4 v[3];
  float s = 0.f, ss = 0.f;
#pragma unroll
  for (int i = 0; i < 3; ++i) {
    v[i] = *(const float4*)&fr[(i * 64 + lane) * 4];
    s  += v[i].x + v[i].y + v[i].z + v[i].w;
    ss += v[i].x * v[i].x + v[i].y * v[i].y + v[i].z * v[i].z + v[i].w * v[i].w;
  }
#pragma unroll
  for (int off = 32; off; off >>= 1) {
    s  += __shfl_xor(s, off);
    ss += __shfl_xor(ss, off);
  }
  const float mu = s * (1.f / 768.f);
  const float var = ss * (1.f / 768.f) - mu * mu;
  const float rs = rsqrtf(var + LNEPS);
#pragma unroll
  for (int i = 0; i < 3; ++i) {
    const int idx = (i * 64 + lane) * 4;
    float4 g4 = *(const float4*)&gamma[idx];
    float4 b4 = *(const float4*)&beta[idx];
    half4 o;
    o[0] = (_Float16)((v[i].x - mu) * rs * g4.x + b4.x);
    o[1] = (_Float16)((v[i].y - mu) * rs * g4.y + b4.y);
    o[2] = (_Float16)((v[i].z - mu) * rs * g4.z + b4.z);
    o[3] = (_Float16)((v[i].w - mu) * rs * g4.w + b4.w);
    *(half4*)&xout[row * HDIM + idx] = o;
  }
}

// ---------------- fused panel GEMM + attention + output ----------------
// Block = 192 rows (64 batches) x 2304 fused cols in 9 n-tiles of 256.
// 512 threads / 8 waves (2M x 4N, wave tile 96x64), depth-2 prefetch with
// per-group counted vmcnt(3)/vmcnt(4), raw barriers, zero-conflict XOR layout.
// R16 (final): K-loop unrolled x2 with STATIC buffer indices (all LDS offsets
// fold to immediates); verified best configuration (1193.6 us total w/ R20).
__global__ __launch_bounds__(512, 1) void fused_kernel(
    const _Float16* __restrict__ xh,
    const _Float16* __restrict__ Wf,
    const float* __restrict__ bias,
    const float* __restrict__ bo,
    float* __restrict__ out)
{
  __shared__ __align__(16) char lds[L_TOT];
  const int tid = threadIdx.x;
  const int lane = tid & 63;
  const int quad = lane >> 4, l16 = lane & 15;
  const int w = tid >> 6;
  const int wm = w >> 2, wn = w & 3;

  const int nwg = gridDim.x;
  const int orig = blockIdx.x;
  const int bid = (orig & 7) * (nwg >> 3) + (orig >> 3);
  const long m0 = (long)bid * 192;

  // zero score accumulators (sp+sn contiguous: 1152 floats)
  {
    float* sc = (float*)(lds + L_SP);
#pragma unroll
    for (int i = 0; i < 3; ++i) {
      const int idx = i * 512 + tid;
      if (idx < 1152) sc[idx] = 0.f;
    }
  }

  // staging maps. A: 768 16B-chunks (192 rows x 4), waves 0-3, 3 issues.
  //               B: 1024 chunks (256 rows x 4), waves 4-7, 4 issues.
  // physical slot p of row r holds logical chunk cc = p ^ ((r>>1)&3).
  const int wg = w & 3;
  long aOff[3]; int aLds[3];
#pragma unroll
  for (int i = 0; i < 3; ++i) {
    const int c = i * 256 + wg * 64 + lane, r = c >> 2, p = c & 3;
    const int cc = p ^ ((r >> 1) & 3);
    aOff[i] = (m0 + r) * HDIM + cc * 8;
    aLds[i] = c * 16;
  }
  long bOff[4]; int bLds[4];
#pragma unroll
  for (int i = 0; i < 4; ++i) {
    const int c = i * 256 + wg * 64 + lane, r = c >> 2, p = c & 3;
    const int cc = p ^ ((r >> 1) & 3);
    bOff[i] = (long)r * HDIM + cc * 8;
    bLds[i] = c * 16;
  }

  long stg_k = 0, stg_nb = 0;
#define STAGE(BUF_)                                                           \
  do {                                                                        \
    if (w < 4) {                                                              \
      _Pragma("unroll")                                                       \
      for (int i_ = 0; i_ < 3; ++i_)                                          \
        gload_lds16(xh + aOff[i_] + stg_k, lds + L_AS + (BUF_) * 12288 + aLds[i_]); \
    } else {                                                                  \
      _Pragma("unroll")                                                       \
      for (int i_ = 0; i_ < 4; ++i_)                                          \
        gload_lds16(Wf + stg_nb + bOff[i_] + stg_k, lds + L_BS + (BUF_) * 16384 + bLds[i_]); \
    }                                                                         \
    stg_k += 32;                                                              \
    if (stg_k == HDIM) { stg_k = 0; stg_nb += 256L * HDIM; }                  \
  } while (0)
#define VMW()                                                                 \
  do { if (w < 4) { asm volatile("s_waitcnt vmcnt(3)" ::: "memory"); }        \
       else       { asm volatile("s_waitcnt vmcnt(4)" ::: "memory"); } } while (0)
#define SB0() __builtin_amdgcn_sched_barrier(0)

  f32x4 acc[6][4];
#pragma unroll
  for (int mi = 0; mi < 6; ++mi)
#pragma unroll
    for (int ni = 0; ni < 4; ++ni)
#pragma unroll
      for (int j = 0; j < 4; ++j) acc[mi][ni][j] = 0.f;

// One K-step with STATIC buffer index BUF_ (runtime step id s_ only gates
// the staging/wait tail). Stage(s+2) targets buf[(s+2)&1] == BUF_.
#define STEPK(BUF_, s_)                                                       \
  do {                                                                        \
    const char* as_ = lds + L_AS + (BUF_) * 12288;                            \
    const char* bs_ = lds + L_BS + (BUF_) * 16384;                            \
    half8 af[6], bf[4];                                                       \
    _Pragma("unroll")                                                         \
    for (int mi_ = 0; mi_ < 6; ++mi_) {                                       \
      const int r_ = wm * 96 + mi_ * 16 + l16;                                \
      af[mi_] = *(const half8*)(as_ + r_ * 64 + ((quad ^ ((r_ >> 1) & 3)) * 16)); \
    }                                                                         \
    _Pragma("unroll")                                                         \
    for (int ni_ = 0; ni_ < 4; ++ni_) {                                       \
      const int r_ = wn * 64 + ni_ * 16 + l16;                                \
      bf[ni_] = *(const half8*)(bs_ + r_ * 64 + ((quad ^ ((r_ >> 1) & 3)) * 16)); \
    }                                                                         \
    __builtin_amdgcn_s_setprio(1);                                            \
    _Pragma("unroll")                                                         \
    for (int mi_ = 0; mi_ < 6; ++mi_)                                         \
      _Pragma("unroll")                                                       \
      for (int ni_ = 0; ni_ < 4; ++ni_)                                       \
        acc[mi_][ni_] = __builtin_amdgcn_mfma_f32_16x16x32_f16(               \
            af[mi_], bf[ni_], acc[mi_][ni_], 0, 0, 0);                        \
    __builtin_amdgcn_s_setprio(0);                                            \
    SB0();                                                                    \
    __builtin_amdgcn_s_barrier();          /* all waves done reading buf */   \
    SB0();                                                                    \
    if ((s_) + 2 < 216) STAGE(BUF_);       /* overwrite just-consumed buf */  \
    if ((s_) < 214) {                                                         \
      VMW();                               /* step s+1 landed */              \
      __builtin_amdgcn_s_barrier();                                           \
      SB0();                                                                  \
    } else if ((s_) == 214) {                                                 \
      asm volatile("s_waitcnt vmcnt(0)" ::: "memory");  /* tail */            \
      __builtin_amdgcn_s_barrier();                                           \
      SB0();                                                                  \
    }                                                                         \
  } while (0)

  STAGE(0); STAGE(1);
  VMW();                                   // K-step 0 landed (own loads)
  __builtin_amdgcn_s_barrier();
  SB0();

  for (int n = 0; n < 9; ++n) {
    for (int ks2 = 0; ks2 < 12; ++ks2) {
      const int sbase = n * 24 + ks2 * 2;
      STEPK(0, sbase);
      STEPK(1, sbase + 1);
    }

    // ---- phase end for n-tile n: bias + stash write (fp16), zero acc ----
    {
      float bv[4];
#pragma unroll
      for (int ni = 0; ni < 4; ++ni)
        bv[ni] = bias[n * 256 + wn * 64 + ni * 16 + l16];
      char* st = lds + ((wn >> 1) ? L_STK : L_STQ);
      const int cb = (wn & 1) * 64;
#pragma unroll
      for (int mi = 0; mi < 6; ++mi)
#pragma unroll
        for (int ni = 0; ni < 4; ++ni)
#pragma unroll
          for (int j = 0; j < 4; ++j) {
            const int row = wm * 96 + mi * 16 + quad * 4 + j;
            *(_Float16*)(st + row * SSTR + (cb + ni * 16 + l16) * 2) =
                (_Float16)(acc[mi][ni][j] + bv[ni]);
          }
#pragma unroll
      for (int mi = 0; mi < 6; ++mi)
#pragma unroll
        for (int ni = 0; ni < 4; ++ni)
#pragma unroll
          for (int j = 0; j < 4; ++j) acc[mi][ni][j] = 0.f;
    }
    __builtin_amdgcn_s_barrier();

    if (n < 6) {
      // score accumulation: 8 threads per batch, each a 16-elem h-segment
      const int b = tid >> 3, sub = tid & 7;
      half4 qv[3][4], kv[3][4];
#pragma unroll
      for (int t = 0; t < 3; ++t) {
        const char* rq = lds + L_STQ + (3 * b + t) * SSTR + sub * 32;
        const char* rk = lds + L_STK + (3 * b + t) * SSTR + sub * 32;
#pragma unroll
        for (int u = 0; u < 4; ++u) {
          qv[t][u] = *(const half4*)(rq + u * 8);
          kv[t][u] = *(const half4*)(rk + u * 8);
        }
      }
#pragma unroll
      for (int qi = 0; qi < 3; ++qi)
#pragma unroll
        for (int ki = 0; ki < 3; ++ki) {
          float p = 0.f, nn = 0.f;
#pragma unroll
          for (int u = 0; u < 4; ++u)
#pragma unroll
            for (int e = 0; e < 4; ++e) {
              const float qq = (float)qv[qi][u][e];
              const float kk = (float)kv[ki][u][e];
              p  += fmaxf(qq, 0.f) * fmaxf(kk, 0.f);
              nn += fminf(qq, 0.f) * fminf(kk, 0.f);
            }
          p  += __shfl_xor(p, 1);  p  += __shfl_xor(p, 2);  p  += __shfl_xor(p, 4);
          nn += __shfl_xor(nn, 1); nn += __shfl_xor(nn, 2); nn += __shfl_xor(nn, 4);
          if (sub == 0) {
            ((float*)(lds + L_SP))[b * 9 + qi * 3 + ki] += p;
            ((float*)(lds + L_SN))[b * 9 + qi * 3 + ki] += nn;
          }
        }
      __builtin_amdgcn_s_barrier();
      if (n == 5) {
        if (tid < 64) {   // softmax coefs; coef overwrites sp in place
          float* sp = (float*)(lds + L_SP) + tid * 9;
          float* sn = (float*)(lds + L_SN) + tid * 9;
          const float scale = 0.03608439182435161f;  // 768^-0.5
#pragma unroll
          for (int qi = 0; qi < 3; ++qi) {
            const float p0 = sp[qi*3+0]*scale, p1 = sp[qi*3+1]*scale, p2 = sp[qi*3+2]*scale;
            const float n0 = sn[qi*3+0]*scale, n1 = sn[qi*3+1]*scale, n2 = sn[qi*3+2]*scale;
            const float mp = fmaxf(p0, fmaxf(p1, p2));
            const float mn = fmaxf(n0, fmaxf(n1, n2));
            const float ep0 = __expf(p0-mp), ep1 = __expf(p1-mp), ep2 = __expf(p2-mp);
            const float en0 = __expf(n0-mn), en1 = __expf(n1-mn), en2 = __expf(n2-mn);
            const float rp = 1.f / (ep0+ep1+ep2), rn = 1.f / (en0+en1+en2);
            sp[qi*3+0] = ep0*rp - en0*rn;
            sp[qi*3+1] = ep1*rp - en1*rn;
            sp[qi*3+2] = ep2*rp - en2*rn;
          }
        }
        __builtin_amdgcn_s_barrier();
      }
    } else {
      // VO epilogue: out[row] = xh + bo + sum_ki coef[t][ki] * VO[3b+ki]
      const int cg = tid & 63, rg = tid >> 6;     // 64 col-groups x 8 row-groups
      const int c = cg * 4;
      const char* vb = lds + ((c >> 7) ? L_STK : L_STQ) + (c & 127) * 2;
      const long gc = 256L * (n - 6) + c;
      const f32x4 bov = *(const f32x4*)&bo[gc];
      const float* cf0 = (const float*)(lds + L_SP);
#pragma unroll 4
      for (int rr = 0; rr < 24; ++rr) {
        const int row = rr * 8 + rg;
        const int b = (int)((unsigned)row / 3u);
        const int t = row - 3 * b;
        const float* cf = cf0 + b * 9 + t * 3;
        const half4 v0 = *(const half4*)(vb + (3 * b + 0) * SSTR);
        const half4 v1 = *(const half4*)(vb + (3 * b + 1) * SSTR);
        const half4 v2 = *(const half4*)(vb + (3 * b + 2) * SSTR);
        const half4 hx = *(const half4*)&xh[(m0 + row) * HDIM + gc];
        const float c0 = cf[0], c1 = cf[1], c2 = cf[2];
        f32x4 o;
#pragma unroll
        for (int j = 0; j < 4; ++j)
          o[j] = (float)hx[j] + bov[j] + c0 * (float)v0[j]
               + c1 * (float)v1[j] + c2 * (float)v2[j];
        *(f32x4*)&out[(m0 + row) * HDIM + gc] = o;
      }
      __builtin_amdgcn_s_barrier();
    }
  }
#undef STAGE
#undef VMW
#undef SB0
#undef STEPK
}

extern "C" void kernel_launch(void* const* d_in, const int* in_sizes, int n_in,
                              void* d_out, int out_size, void* d_ws, size_t ws_size,
                              hipStream_t stream) {
  (void)in_sizes; (void)n_in; (void)out_size; (void)ws_size;
  const float* feat = (const float*)d_in[0];
  const float* Wq   = (const float*)d_in[1];
  const float* bq   = (const float*)d_in[2];
  const float* Wk   = (const float*)d_in[3];
  const float* bk   = (const float*)d_in[4];
  const float* Wv   = (const float*)d_in[5];
  const float* bv   = (const float*)d_in[6];
  const float* Wo   = (const float*)d_in[7];
  const float* bo   = (const float*)d_in[8];
  const float* ln_g = (const float*)d_in[9];
  const float* ln_b = (const float*)d_in[10];

  char* ws = (char*)d_ws;
  // layout: xh [196608*768] fp16 @ 0            (301,989,888)
  //         Wf [2304*768]  fp16 @ 301,989,888   (3,538,944)
  //         biasf [2304]   fp32 @ 305,528,832   (9,216)
  _Float16* xh    = (_Float16*)(ws);
  _Float16* Wf    = (_Float16*)(ws + 301989888L);
  float*    biasf = (float*)   (ws + 305528832L);

  wvo_kernel<<<145, 256, 0, stream>>>(Wo, Wv, bv, Wf + 1536L * 768, biasf + 1536);
  // prep: LN (49152 blocks) + QK weight convert (4614 blocks) in one dispatch
  prep_kernel<<<53766, 256, 0, stream>>>(feat, ln_g, ln_b, xh,
                                         Wq, Wk, bq, bk, Wf, biasf);
  fused_kernel<<<1024, 512, 0, stream>>>(xh, Wf, biasf, bo, (float*)d_out);
}